// Round 5
// baseline (1312.277 us; speedup 1.0000x reference)
//
#include <hip/hip_runtime.h>
#include <hip/hip_bf16.h>
#include <math.h>

// Problem constants (B=1, S=2048, D=1024, E=8, K=2, FF=4096)
#define T_      2048
#define D_      1024
#define E_      8
#define FF_     4096
#define M_      64                   // tokens per tile
#define TILES_  (T_ / M_)            // 32 capacity tiles per expert
#define CH1_    (FF_ / 128)          // 32 ff-chunks (128 ff each) in K1
#define DS_     8                    // d-splits (128 d each) in K2
#define TRS_    24                   // transpose LDS row stride (shorts)

typedef __attribute__((ext_vector_type(8))) short  bf16x8;   // MFMA A/B frag
typedef __attribute__((ext_vector_type(4))) float  f32x4;    // MFMA C/D frag
typedef __attribute__((ext_vector_type(8))) float  f32x8;
typedef __attribute__((ext_vector_type(8))) __bf16 b16x8;
typedef __attribute__((ext_vector_type(4))) __bf16 b16x4;

static __device__ inline bf16x8 cvt8(float4 a, float4 b) {
    f32x8 x;
    x[0] = a.x; x[1] = a.y; x[2] = a.z; x[3] = a.w;
    x[4] = b.x; x[5] = b.y; x[6] = b.z; x[7] = b.w;
    b16x8 c = __builtin_convertvector(x, b16x8);   // RNE packed cvt
    return *(bf16x8*)&c;
}

// ---------------------------------------------------------------------------
// Router (fp32): logits, top-2 + renorm, per-expert (token, weight) lists.
// Also converts h -> bf16 (hbf) so the GEMM kernels skip LDS staging.
// Softmax denom cancels in top-2 renorm: w0 = 1/(1+exp(l1-l0)).
// ---------------------------------------------------------------------------
__global__ __launch_bounds__(256) void router_kernel(
    const float* __restrict__ h, const float* __restrict__ gw,
    __bf16* __restrict__ hbf, float* __restrict__ logits,
    int* __restrict__ counts, int* __restrict__ lists, float* __restrict__ wlist)
{
    int t = blockIdx.x * 4 + (threadIdx.x >> 6);
    int lane = threadIdx.x & 63;
    const float4* hrow = (const float4*)(h + (size_t)t * D_);   // 256 float4
    const float4* gw4  = (const float4*)gw;                     // [E][256]
    float part[E_];
#pragma unroll
    for (int e = 0; e < E_; ++e) part[e] = 0.f;
#pragma unroll 4
    for (int i = lane; i < 256; i += 64) {
        float4 v = hrow[i];
        f32x4 vv; vv[0] = v.x; vv[1] = v.y; vv[2] = v.z; vv[3] = v.w;
        b16x4 bv = __builtin_convertvector(vv, b16x4);
        *(b16x4*)(hbf + (size_t)t * D_ + i * 4) = bv;
#pragma unroll
        for (int e = 0; e < E_; ++e) {
            float4 g = gw4[e * 256 + i];
            part[e] += v.x * g.x + v.y * g.y + v.z * g.z + v.w * g.w;
        }
    }
#pragma unroll
    for (int e = 0; e < E_; ++e) {
        float v = part[e];
#pragma unroll
        for (int off = 32; off > 0; off >>= 1) v += __shfl_down(v, off, 64);
        part[e] = v;
    }
    if (lane == 0) {
        float* lo = logits + (size_t)t * E_;
#pragma unroll
        for (int e = 0; e < E_; ++e) lo[e] = part[e];
        int i0 = 0;
#pragma unroll
        for (int e = 1; e < E_; ++e) if (part[e] > part[i0]) i0 = e;
        int i1 = (i0 == 0) ? 1 : 0;
#pragma unroll
        for (int e = 0; e < E_; ++e)
            if (e != i0 && part[e] > part[i1]) i1 = e;
        float w1v = expf(part[i1] - part[i0]);
        float s = 1.0f + w1v;
        int p0 = atomicAdd(&counts[i0], 1);
        lists[i0 * T_ + p0] = t; wlist[i0 * T_ + p0] = 1.0f / s;
        int p1 = atomicAdd(&counts[i1], 1);
        lists[i1 * T_ + p1] = t; wlist[i1 * T_ + p1] = w1v / s;
    }
}

// Exclusive prefix of counts -> offs (8 values; trivial)
__global__ void prefix_kernel(const int* __restrict__ counts, int* __restrict__ offs) {
    if (threadIdx.x == 0) {
        int s = 0;
#pragma unroll
        for (int e = 0; e < E_; ++e) { offs[e] = s; s += counts[e]; }
    }
}

// ---------------------------------------------------------------------------
// K1: inter[row][ff] = silu(h@w1^T) * (h@w3^T), bf16, compact rows.
// Block = (e, ff-chunk of 128, 64-token tile); 8 waves, wave w owns 16 ff.
// No block barrier; A-frags gathered from hbf (L2-resident); per-wave LDS
// transpose converts MFMA C-layout -> token-major layout.
// Per-wave tile = 16 tokens x 16 ff = 256 bf16 -> each lane reads b16x4
// (64 x 4 = 256; b16x8 would over-read into the next wave's columns).
// MFMA 16x16x32 bf16 (m89/m91): A: lane=A[m=ln][k=q*8+j];
//   B: lane=B[k=q*8+j][n=ln]; C/D: col=ln, row=q*4+reg.
// ---------------------------------------------------------------------------
__global__ __launch_bounds__(512) void gemm1_kernel(
    const __bf16* __restrict__ hbf, const float* __restrict__ w1,
    const float* __restrict__ w3, const int* __restrict__ counts,
    const int* __restrict__ offs, const int* __restrict__ lists,
    __bf16* __restrict__ inter)
{
    int bid  = blockIdx.x;
    int s    = bid & 255;       // slice id = e*CH1_+ch (same slice -> same XCD)
    int tile = bid >> 8;
    int ch   = s & 31;
    int e    = s >> 5;
    int ne   = counts[e];
    if (tile * M_ >= ne) return;
    int gb = offs[e];

    __shared__ __bf16 tr[8 * 16 * TRS_];   // 6 KB: per-wave 16x16 transpose tiles

    int tid = threadIdx.x, lane = tid & 63, w = tid >> 6;
    int ln = lane & 15, q = lane >> 4;

    // per-lane gathered token rows (A-frag row = ln within each 16-token group)
    const __bf16* ap[4];
#pragma unroll
    for (int mt = 0; mt < 4; ++mt) {
        int idx = tile * M_ + mt * 16 + ln;
        int c   = idx < ne ? idx : ne - 1;
        ap[mt] = hbf + (size_t)lists[e * T_ + c] * D_;
    }

    int ffr = ch * 128 + w * 16 + ln;      // this lane's ff row (B n-index)
    const float* w1p = w1 + ((size_t)e * FF_ + ffr) * D_;
    const float* w3p = w3 + ((size_t)e * FF_ + ffr) * D_;

    f32x4 up[4], gt[4];
#pragma unroll
    for (int mt = 0; mt < 4; ++mt) {
        up[mt] = (f32x4){0.f, 0.f, 0.f, 0.f};
        gt[mt] = (f32x4){0.f, 0.f, 0.f, 0.f};
    }

#pragma unroll 4
    for (int kk = 0; kk < 32; ++kk) {
        int ko = kk * 32 + q * 8;
        bf16x8 b1 = cvt8(*(const float4*)(w1p + ko), *(const float4*)(w1p + ko + 4));
        bf16x8 b3 = cvt8(*(const float4*)(w3p + ko), *(const float4*)(w3p + ko + 4));
#pragma unroll
        for (int mt = 0; mt < 4; ++mt) {
            bf16x8 a = *(const bf16x8*)(ap[mt] + ko);
            up[mt] = __builtin_amdgcn_mfma_f32_16x16x32_bf16(a, b1, up[mt], 0, 0, 0);
            gt[mt] = __builtin_amdgcn_mfma_f32_16x16x32_bf16(a, b3, gt[mt], 0, 0, 0);
        }
    }

    // epilogue: silu*gate, per-wave transpose (C-layout -> token-major), store
    __bf16* trw = &tr[w * 16 * TRS_];
    int colbase = ch * 128 + w * 16;
#pragma unroll
    for (int mt = 0; mt < 4; ++mt) {
#pragma unroll
        for (int r = 0; r < 4; ++r) {
            float u = up[mt][r], g = gt[mt][r];
            float val = (u / (1.f + expf(-u))) * g;     // silu(u)*g
            trw[(q * 4 + r) * TRS_ + ln] = (__bf16)val; // row=token, col=ff
        }
        __asm__ volatile("s_waitcnt lgkmcnt(0)" ::: "memory");
        // lane (q,ln): token=ln, ff group q*4 (4 shorts = 8B, aligned)
        b16x4 v4 = *(b16x4*)&trw[ln * TRS_ + q * 4];
        int idx = tile * M_ + mt * 16 + ln;
        if (idx < ne)
            *(b16x4*)(inter + (size_t)(gb + idx) * FF_ + colbase + q * 4) = v4;
        __asm__ volatile("s_waitcnt lgkmcnt(0)" ::: "memory");
    }
}

// ---------------------------------------------------------------------------
// K2: out[t][d] += cw * (inter[row] . w2[e][d]), K = full FF per block.
// Block = (e, d-slice of 128, 64-token tile); 8 waves, wave w owns 16 d.
// Tiny registers/LDS -> high occupancy; 2 atomicAdds per out element total.
// ---------------------------------------------------------------------------
__global__ __launch_bounds__(512) void gemm2_kernel(
    const __bf16* __restrict__ inter, const float* __restrict__ w2,
    const int* __restrict__ counts, const int* __restrict__ offs,
    const int* __restrict__ lists, const float* __restrict__ wlist,
    float* __restrict__ out)
{
    int bid  = blockIdx.x;
    int s    = bid & 63;        // slice id = e*DS_+ds (same slice -> same XCD)
    int tile = bid >> 6;
    int ds   = s & 7;
    int e    = s >> 3;
    int ne   = counts[e];
    if (tile * M_ >= ne) return;
    int gb = offs[e];

    __shared__ int   stok[M_];
    __shared__ float swgt[M_];

    int tid = threadIdx.x, lane = tid & 63, w = tid >> 6;
    int ln = lane & 15, q = lane >> 4;

    if (tid < M_) {
        int idx = tile * M_ + tid;
        int c   = idx < ne ? idx : ne - 1;
        stok[tid] = lists[e * T_ + c];
        swgt[tid] = (idx < ne) ? wlist[e * T_ + idx] : 0.f;
    }
    __syncthreads();

    const __bf16* ap[4];
#pragma unroll
    for (int mt = 0; mt < 4; ++mt) {
        int idx = tile * M_ + mt * 16 + ln;
        int c   = idx < ne ? idx : ne - 1;
        ap[mt] = inter + (size_t)(gb + c) * FF_;
    }

    int dcol = ds * 128 + w * 16 + ln;     // lane's d (B n-index)
    const float* w2p = w2 + ((size_t)e * D_ + dcol) * FF_;

    f32x4 acc[4];
#pragma unroll
    for (int mt = 0; mt < 4; ++mt) acc[mt] = (f32x4){0.f, 0.f, 0.f, 0.f};

#pragma unroll 4
    for (int kk = 0; kk < 128; ++kk) {
        int ko = kk * 32 + q * 8;
        bf16x8 b = cvt8(*(const float4*)(w2p + ko), *(const float4*)(w2p + ko + 4));
#pragma unroll
        for (int mt = 0; mt < 4; ++mt) {
            bf16x8 a = *(const bf16x8*)(ap[mt] + ko);
            acc[mt] = __builtin_amdgcn_mfma_f32_16x16x32_bf16(a, b, acc[mt], 0, 0, 0);
        }
    }

    // epilogue: C/D row=q*4+r (token), col=ln (d)
#pragma unroll
    for (int mt = 0; mt < 4; ++mt) {
#pragma unroll
        for (int r = 0; r < 4; ++r) {
            int m = mt * 16 + q * 4 + r;
            float wgt = swgt[m];
            if (wgt != 0.f)
                atomicAdd(out + (size_t)stok[m] * D_ + dcol, wgt * acc[mt][r]);
        }
    }
}

extern "C" void kernel_launch(void* const* d_in, const int* in_sizes, int n_in,
                              void* d_out, int out_size, void* d_ws, size_t ws_size,
                              hipStream_t stream)
{
    const float* h  = (const float*)d_in[0];   // [1,2048,1024]
    const float* gw = (const float*)d_in[1];   // [8,1024]
    const float* w1 = (const float*)d_in[2];   // [8,4096,1024]
    const float* w3 = (const float*)d_in[3];   // [8,4096,1024]
    const float* w2 = (const float*)d_in[4];   // [8,1024,4096]

    float* out    = (float*)d_out;             // [2048*1024] then logits
    float* logits = out + (size_t)T_ * D_;     // [2048*8]

    // workspace layout (≈38 MB)
    char*   ws     = (char*)d_ws;
    int*    counts = (int*)ws;                                   // @0      (32 B)
    int*    offs   = (int*)(ws + 128);                           // @128    (32 B)
    int*    lists  = (int*)(ws + 256);                           // @256    (64 KB)
    float*  wlist  = (float*)(ws + 256 + E_ * T_ * 4);           // +64 KB
    __bf16* hbf    = (__bf16*)(ws + 256 + 2 * E_ * T_ * 4);      // 4 MB
    __bf16* inter  = (__bf16*)(ws + 256 + 2 * E_ * T_ * 4
                               + (size_t)T_ * D_ * 2);           // 32 MB (2T rows)

    hipMemsetAsync(counts, 0, 256, stream);
    hipMemsetAsync(out, 0, (size_t)T_ * D_ * sizeof(float), stream);

    router_kernel<<<T_ / 4, 256, 0, stream>>>(h, gw, hbf, logits, counts, lists, wlist);
    prefix_kernel<<<1, 64, 0, stream>>>(counts, offs);
    gemm1_kernel<<<TILES_ * E_ * CH1_, 512, 0, stream>>>(hbf, w1, w3, counts, offs,
                                                         lists, inter);
    gemm2_kernel<<<TILES_ * E_ * DS_, 512, 0, stream>>>(inter, w2, counts, offs,
                                                        lists, wlist, out);
}

// Round 6
// 1202.132 us; speedup vs baseline: 1.0916x; 1.0916x over previous
//
#include <hip/hip_runtime.h>
#include <hip/hip_bf16.h>
#include <math.h>

// Problem constants (B=1, S=2048, D=1024, E=8, K=2, FF=4096)
#define T_      2048
#define D_      1024
#define E_      8
#define FF_     4096
#define M_      64                   // tokens per tile
#define TILES_  (T_ / M_)            // 32 capacity tiles per expert
#define CH1_    (FF_ / 128)          // 32 ff-chunks (128 ff each) in K1
#define DS_     8                    // d-splits (128 d each) in K2
#define TRS_    24                   // transpose LDS row stride (shorts)

typedef __attribute__((ext_vector_type(8))) short  bf16x8;   // MFMA A/B frag
typedef __attribute__((ext_vector_type(4))) float  f32x4;    // MFMA C/D frag
typedef __attribute__((ext_vector_type(8))) float  f32x8;
typedef __attribute__((ext_vector_type(8))) __bf16 b16x8;
typedef __attribute__((ext_vector_type(4))) __bf16 b16x4;

static __device__ inline bf16x8 cvt8(float4 a, float4 b) {
    f32x8 x;
    x[0] = a.x; x[1] = a.y; x[2] = a.z; x[3] = a.w;
    x[4] = b.x; x[5] = b.y; x[6] = b.z; x[7] = b.w;
    b16x8 c = __builtin_convertvector(x, b16x8);   // RNE packed cvt
    return *(bf16x8*)&c;
}

// load one MFMA B-fragment (8 elems at rowptr+ko), fp32->cvt or direct bf16
template <bool BF>
static __device__ inline bf16x8 ldfrag(const void* rowptr, int ko) {
    if constexpr (BF) {
        return *(const bf16x8*)((const __bf16*)rowptr + ko);
    } else {
        const float* f = (const float*)rowptr + ko;
        return cvt8(*(const float4*)f, *(const float4*)(f + 4));
    }
}

// ---------------------------------------------------------------------------
// fp32 -> bf16 bulk conversion (layout-preserving), grid-stride.
// ---------------------------------------------------------------------------
__global__ __launch_bounds__(256) void cvt_kernel(
    const float4* __restrict__ src, b16x4* __restrict__ dst, int n4)
{
    int i = blockIdx.x * 256 + threadIdx.x;
    int stride = gridDim.x * 256;
    for (; i < n4; i += stride) {
        float4 v = src[i];
        f32x4 vv; vv[0] = v.x; vv[1] = v.y; vv[2] = v.z; vv[3] = v.w;
        dst[i] = __builtin_convertvector(vv, b16x4);
    }
}

// ---------------------------------------------------------------------------
// Router (fp32): logits, top-2 + renorm, per-expert (token, weight) lists.
// Also converts h -> bf16 (hbf). Softmax denom cancels in top-2 renorm.
// ---------------------------------------------------------------------------
__global__ __launch_bounds__(256) void router_kernel(
    const float* __restrict__ h, const float* __restrict__ gw,
    __bf16* __restrict__ hbf, float* __restrict__ logits,
    int* __restrict__ counts, int* __restrict__ lists, float* __restrict__ wlist)
{
    int t = blockIdx.x * 4 + (threadIdx.x >> 6);
    int lane = threadIdx.x & 63;
    const float4* hrow = (const float4*)(h + (size_t)t * D_);   // 256 float4
    const float4* gw4  = (const float4*)gw;                     // [E][256]
    float part[E_];
#pragma unroll
    for (int e = 0; e < E_; ++e) part[e] = 0.f;
#pragma unroll 4
    for (int i = lane; i < 256; i += 64) {
        float4 v = hrow[i];
        f32x4 vv; vv[0] = v.x; vv[1] = v.y; vv[2] = v.z; vv[3] = v.w;
        b16x4 bv = __builtin_convertvector(vv, b16x4);
        *(b16x4*)(hbf + (size_t)t * D_ + i * 4) = bv;
#pragma unroll
        for (int e = 0; e < E_; ++e) {
            float4 g = gw4[e * 256 + i];
            part[e] += v.x * g.x + v.y * g.y + v.z * g.z + v.w * g.w;
        }
    }
#pragma unroll
    for (int e = 0; e < E_; ++e) {
        float v = part[e];
#pragma unroll
        for (int off = 32; off > 0; off >>= 1) v += __shfl_down(v, off, 64);
        part[e] = v;
    }
    if (lane == 0) {
        float* lo = logits + (size_t)t * E_;
#pragma unroll
        for (int e = 0; e < E_; ++e) lo[e] = part[e];
        int i0 = 0;
#pragma unroll
        for (int e = 1; e < E_; ++e) if (part[e] > part[i0]) i0 = e;
        int i1 = (i0 == 0) ? 1 : 0;
#pragma unroll
        for (int e = 0; e < E_; ++e)
            if (e != i0 && part[e] > part[i1]) i1 = e;
        float w1v = expf(part[i1] - part[i0]);
        float s = 1.0f + w1v;
        int p0 = atomicAdd(&counts[i0], 1);
        lists[i0 * T_ + p0] = t; wlist[i0 * T_ + p0] = 1.0f / s;
        int p1 = atomicAdd(&counts[i1], 1);
        lists[i1 * T_ + p1] = t; wlist[i1 * T_ + p1] = w1v / s;
    }
}

// Exclusive prefix of counts -> offs (8 values; trivial)
__global__ void prefix_kernel(const int* __restrict__ counts, int* __restrict__ offs) {
    if (threadIdx.x == 0) {
        int s = 0;
#pragma unroll
        for (int e = 0; e < E_; ++e) { offs[e] = s; s += counts[e]; }
    }
}

// ---------------------------------------------------------------------------
// K1: inter[row][ff] = silu(h@w1^T) * (h@w3^T), bf16, compact rows.
// Block = (e, ff-chunk of 128, 64-token tile); 8 waves, wave w owns 16 ff.
// BF=true: weights already bf16 (L3-resident) -> B-frag = one dwordx4/lane.
// MFMA 16x16x32 bf16 (m89/m91): A: lane=A[m=ln][k=q*8+j];
//   B: lane=B[k=q*8+j][n=ln]; C/D: col=ln, row=q*4+reg.
// ---------------------------------------------------------------------------
template <bool BF>
__global__ __launch_bounds__(512) void gemm1_kernel(
    const __bf16* __restrict__ hbf,
    const float* __restrict__ w1f, const float* __restrict__ w3f,
    const __bf16* __restrict__ w1b, const __bf16* __restrict__ w3b,
    const int* __restrict__ counts, const int* __restrict__ offs,
    const int* __restrict__ lists, __bf16* __restrict__ inter)
{
    int bid  = blockIdx.x;
    int s    = bid & 255;       // slice id = e*CH1_+ch (same slice -> same XCD)
    int tile = bid >> 8;
    int ch   = s & 31;
    int e    = s >> 5;
    int ne   = counts[e];
    if (tile * M_ >= ne) return;
    int gb = offs[e];

    __shared__ __bf16 tr[8 * 16 * TRS_];   // 6 KB: per-wave 16x16 transpose tiles

    int tid = threadIdx.x, lane = tid & 63, w = tid >> 6;
    int ln = lane & 15, q = lane >> 4;

    const __bf16* ap[4];
#pragma unroll
    for (int mt = 0; mt < 4; ++mt) {
        int idx = tile * M_ + mt * 16 + ln;
        int c   = idx < ne ? idx : ne - 1;
        ap[mt] = hbf + (size_t)lists[e * T_ + c] * D_;
    }

    int ffr = ch * 128 + w * 16 + ln;      // this lane's ff row (B n-index)
    const void* w1p; const void* w3p;
    if constexpr (BF) {
        w1p = (const void*)(w1b + ((size_t)e * FF_ + ffr) * D_);
        w3p = (const void*)(w3b + ((size_t)e * FF_ + ffr) * D_);
    } else {
        w1p = (const void*)(w1f + ((size_t)e * FF_ + ffr) * D_);
        w3p = (const void*)(w3f + ((size_t)e * FF_ + ffr) * D_);
    }

    f32x4 up[4], gt[4];
#pragma unroll
    for (int mt = 0; mt < 4; ++mt) {
        up[mt] = (f32x4){0.f, 0.f, 0.f, 0.f};
        gt[mt] = (f32x4){0.f, 0.f, 0.f, 0.f};
    }

#pragma unroll 4
    for (int kk = 0; kk < 32; ++kk) {
        int ko = kk * 32 + q * 8;
        bf16x8 b1 = ldfrag<BF>(w1p, ko);
        bf16x8 b3 = ldfrag<BF>(w3p, ko);
#pragma unroll
        for (int mt = 0; mt < 4; ++mt) {
            bf16x8 a = *(const bf16x8*)(ap[mt] + ko);
            up[mt] = __builtin_amdgcn_mfma_f32_16x16x32_bf16(a, b1, up[mt], 0, 0, 0);
            gt[mt] = __builtin_amdgcn_mfma_f32_16x16x32_bf16(a, b3, gt[mt], 0, 0, 0);
        }
    }

    // epilogue: silu*gate, per-wave transpose (C-layout -> token-major), store.
    // per-wave tile = 16 tok x 16 ff = 256 vals -> b16x4 per lane (64*4=256).
    __bf16* trw = &tr[w * 16 * TRS_];
    int colbase = ch * 128 + w * 16;
#pragma unroll
    for (int mt = 0; mt < 4; ++mt) {
#pragma unroll
        for (int r = 0; r < 4; ++r) {
            float u = up[mt][r], g = gt[mt][r];
            float val = (u / (1.f + expf(-u))) * g;     // silu(u)*g
            trw[(q * 4 + r) * TRS_ + ln] = (__bf16)val; // row=token, col=ff
        }
        __asm__ volatile("s_waitcnt lgkmcnt(0)" ::: "memory");
        b16x4 v4 = *(b16x4*)&trw[ln * TRS_ + q * 4];    // token=ln, ff grp q*4
        int idx = tile * M_ + mt * 16 + ln;
        if (idx < ne)
            *(b16x4*)(inter + (size_t)(gb + idx) * FF_ + colbase + q * 4) = v4;
        __asm__ volatile("s_waitcnt lgkmcnt(0)" ::: "memory");
    }
}

// ---------------------------------------------------------------------------
// K2: out[t][d] += cw * (inter[row] . w2[e][d]), K = full FF per block.
// Block = (e, d-slice of 128, 64-token tile); 8 waves, wave w owns 16 d.
// ---------------------------------------------------------------------------
template <bool BF>
__global__ __launch_bounds__(512) void gemm2_kernel(
    const __bf16* __restrict__ inter,
    const float* __restrict__ w2f, const __bf16* __restrict__ w2b,
    const int* __restrict__ counts, const int* __restrict__ offs,
    const int* __restrict__ lists, const float* __restrict__ wlist,
    float* __restrict__ out)
{
    int bid  = blockIdx.x;
    int s    = bid & 63;        // slice id = e*DS_+ds (same slice -> same XCD)
    int tile = bid >> 6;
    int ds   = s & 7;
    int e    = s >> 3;
    int ne   = counts[e];
    if (tile * M_ >= ne) return;
    int gb = offs[e];

    __shared__ int   stok[M_];
    __shared__ float swgt[M_];

    int tid = threadIdx.x, lane = tid & 63, w = tid >> 6;
    int ln = lane & 15, q = lane >> 4;

    if (tid < M_) {
        int idx = tile * M_ + tid;
        int c   = idx < ne ? idx : ne - 1;
        stok[tid] = lists[e * T_ + c];
        swgt[tid] = (idx < ne) ? wlist[e * T_ + idx] : 0.f;
    }
    __syncthreads();

    const __bf16* ap[4];
#pragma unroll
    for (int mt = 0; mt < 4; ++mt) {
        int idx = tile * M_ + mt * 16 + ln;
        int c   = idx < ne ? idx : ne - 1;
        ap[mt] = inter + (size_t)(gb + c) * FF_;
    }

    int dcol = ds * 128 + w * 16 + ln;     // lane's d (B n-index)
    const void* w2p;
    if constexpr (BF) w2p = (const void*)(w2b + ((size_t)e * D_ + dcol) * FF_);
    else              w2p = (const void*)(w2f + ((size_t)e * D_ + dcol) * FF_);

    f32x4 acc[4];
#pragma unroll
    for (int mt = 0; mt < 4; ++mt) acc[mt] = (f32x4){0.f, 0.f, 0.f, 0.f};

#pragma unroll 4
    for (int kk = 0; kk < 128; ++kk) {
        int ko = kk * 32 + q * 8;
        bf16x8 b = ldfrag<BF>(w2p, ko);
#pragma unroll
        for (int mt = 0; mt < 4; ++mt) {
            bf16x8 a = *(const bf16x8*)(ap[mt] + ko);
            acc[mt] = __builtin_amdgcn_mfma_f32_16x16x32_bf16(a, b, acc[mt], 0, 0, 0);
        }
    }

    // epilogue: C/D row=q*4+r (token), col=ln (d)
#pragma unroll
    for (int mt = 0; mt < 4; ++mt) {
#pragma unroll
        for (int r = 0; r < 4; ++r) {
            int m = mt * 16 + q * 4 + r;
            float wgt = swgt[m];
            if (wgt != 0.f)
                atomicAdd(out + (size_t)stok[m] * D_ + dcol, wgt * acc[mt][r]);
        }
    }
}

extern "C" void kernel_launch(void* const* d_in, const int* in_sizes, int n_in,
                              void* d_out, int out_size, void* d_ws, size_t ws_size,
                              hipStream_t stream)
{
    const float* h  = (const float*)d_in[0];   // [1,2048,1024]
    const float* gw = (const float*)d_in[1];   // [8,1024]
    const float* w1 = (const float*)d_in[2];   // [8,4096,1024]
    const float* w3 = (const float*)d_in[3];   // [8,4096,1024]
    const float* w2 = (const float*)d_in[4];   // [8,1024,4096]

    float* out    = (float*)d_out;             // [2048*1024] then logits
    float* logits = out + (size_t)T_ * D_;     // [2048*8]

    // workspace layout
    const size_t W_ELEMS = (size_t)E_ * FF_ * D_;            // 33.55 M per tensor
    char*   ws     = (char*)d_ws;
    size_t  off    = 0;
    int*    counts = (int*)(ws + off); off += 128;
    int*    offs   = (int*)(ws + off); off += 128;
    int*    lists  = (int*)(ws + off); off += (size_t)E_ * T_ * 4;
    float*  wlist  = (float*)(ws + off); off += (size_t)E_ * T_ * 4;
    __bf16* hbf    = (__bf16*)(ws + off); off += (size_t)T_ * D_ * 2;     // 4 MB
    __bf16* inter  = (__bf16*)(ws + off); off += (size_t)T_ * 2 * FF_ * 2; // 32 MB
    size_t  base   = off;
    __bf16* w1b    = (__bf16*)(ws + off); off += W_ELEMS * 2;  // 67 MB
    __bf16* w3b    = (__bf16*)(ws + off); off += W_ELEMS * 2;  // 67 MB
    __bf16* w2b    = (__bf16*)(ws + off); off += W_ELEMS * 2;  // 67 MB
    bool use_bf16 = (ws_size >= off);   // launch-constant -> graph-safe branch
    (void)base;

    hipMemsetAsync(counts, 0, 256, stream);
    hipMemsetAsync(out, 0, (size_t)T_ * D_ * sizeof(float), stream);

    router_kernel<<<T_ / 4, 256, 0, stream>>>(h, gw, hbf, logits, counts, lists, wlist);
    prefix_kernel<<<1, 64, 0, stream>>>(counts, offs);

    if (use_bf16) {
        int n4 = (int)(W_ELEMS / 4);
        cvt_kernel<<<4096, 256, 0, stream>>>((const float4*)w1, (b16x4*)w1b, n4);
        cvt_kernel<<<4096, 256, 0, stream>>>((const float4*)w3, (b16x4*)w3b, n4);
        cvt_kernel<<<4096, 256, 0, stream>>>((const float4*)w2, (b16x4*)w2b, n4);
        gemm1_kernel<true><<<TILES_ * E_ * CH1_, 512, 0, stream>>>(
            hbf, w1, w3, w1b, w3b, counts, offs, lists, inter);
        gemm2_kernel<true><<<TILES_ * E_ * DS_, 512, 0, stream>>>(
            inter, w2, w2b, counts, offs, lists, wlist, out);
    } else {
        gemm1_kernel<false><<<TILES_ * E_ * CH1_, 512, 0, stream>>>(
            hbf, w1, w3, w1b, w3b, counts, offs, lists, inter);
        gemm2_kernel<false><<<TILES_ * E_ * DS_, 512, 0, stream>>>(
            inter, w2, w2b, counts, offs, lists, wlist, out);
    }
}